// Round 11
// baseline (7974.750 us; speedup 1.0000x reference)
//
#include <hip/hip_runtime.h>
#include <hip/hip_bf16.h>
#include <math.h>

#define NN 50000
#define EE 800000
#define GGR 1000
#define FF 16
#define HH 128
#define LL 4

typedef __attribute__((ext_vector_type(8))) short short8;
typedef __attribute__((ext_vector_type(4))) float floatx4;

__device__ __forceinline__ void fma4(float4& a, float s, float4 w) {
  a.x = fmaf(s, w.x, a.x); a.y = fmaf(s, w.y, a.y);
  a.z = fmaf(s, w.z, a.z); a.w = fmaf(s, w.w, a.w);
}
__device__ __forceinline__ float4 relu4(float4 v) {
  return make_float4(fmaxf(v.x, 0.f), fmaxf(v.y, 0.f), fmaxf(v.z, 0.f), fmaxf(v.w, 0.f));
}
__device__ __forceinline__ unsigned short f2bf(float v) {
  __hip_bfloat16 b = __float2bfloat16(v);
  return *reinterpret_cast<unsigned short*>(&b);
}
__device__ __forceinline__ float bf2f(unsigned short u) {
  unsigned int x = ((unsigned int)u) << 16;
  return __uint_as_float(x);
}

__global__ void zero_kernel(float* __restrict__ p, int n) {
  int i = blockIdx.x * blockDim.x + threadIdx.x;
  if (i < n) p[i] = 0.f;
}

// one thread per edge: edge length + in-degree (dst) + out-degree (src) counts
__global__ void edge_prep(const float* __restrict__ pos, const int* __restrict__ src,
                          const int* __restrict__ dst, float* __restrict__ ea,
                          int* __restrict__ deg, int* __restrict__ sdeg) {
  int e = blockIdx.x * 256 + threadIdx.x;
  if (e >= EE) return;
  int s = src[e], d = dst[e];
  float dx = pos[d * 3 + 0] - pos[s * 3 + 0];
  float dy = pos[d * 3 + 1] - pos[s * 3 + 1];
  float dz = pos[d * 3 + 2] - pos[s * 3 + 2];
  ea[e] = sqrtf(dx * dx + dy * dy + dz * dz);
  atomicAdd(&deg[d], 1);
  atomicAdd(&sdeg[s], 1);
}

// exclusive scan of cnt[NN] -> offs[NN+1]; single block of 1024 (generic, used twice)
__global__ __launch_bounds__(1024) void scan_kernel(const int* __restrict__ cnt,
                                                    int* __restrict__ offs) {
  __shared__ int s_part[1024];
  int t = threadIdx.x;
  const int CH = (NN + 1023) / 1024;
  int lo = t * CH;
  int hi = lo + CH; if (hi > NN) hi = NN; if (lo > NN) lo = NN;
  int sum = 0;
  for (int i = lo; i < hi; ++i) sum += cnt[i];
  s_part[t] = sum;
  __syncthreads();
  for (int off = 1; off < 1024; off <<= 1) {
    int v = (t >= off) ? s_part[t - off] : 0;
    __syncthreads();
    s_part[t] += v;
    __syncthreads();
  }
  int run = (t == 0) ? 0 : s_part[t - 1];
  for (int i = lo; i < hi; ++i) { offs[i] = run; run += cnt[i]; }
  if (t == 1023) offs[NN] = s_part[1023];
}

// dst-CSR: assign each edge a slot in its dst bucket; record inverse map slot_of
__global__ void fill_csr(const int* __restrict__ dst, const int* __restrict__ offs,
                         int* __restrict__ cursor, int* __restrict__ eid,
                         int* __restrict__ slot_of) {
  int e = blockIdx.x * 256 + threadIdx.x;
  if (e >= EE) return;
  int d = dst[e];
  int p = atomicAdd(&cursor[d], 1);
  int slot = offs[d] + p;
  eid[slot] = e;
  slot_of[e] = slot;
}

// src-CSR: assign each edge a slot in its src bucket
__global__ void fill_csr2(const int* __restrict__ src, const int* __restrict__ offs2,
                          int* __restrict__ cursor2, int* __restrict__ eid2) {
  int e = blockIdx.x * 256 + threadIdx.x;
  if (e >= EE) return;
  int s = src[e];
  int p = atomicAdd(&cursor2[s], 1);
  eid2[offs2[s] + p] = e;
}

// pack fp32 [Krows x 128] weight into MFMA B-fragment order
__global__ void pack_b(const float* __restrict__ W, int Krows, int ksteps,
                       unsigned short* __restrict__ out) {
  int idx = blockIdx.x * 256 + threadIdx.x;
  int total = ksteps * 4096;
  if (idx >= total) return;
  int j = idx & 7, lane = (idx >> 3) & 63, t = (idx >> 9) & 7, ks = idx >> 12;
  int krow = ks * 32 + (lane >> 4) * 8 + j;
  int n = t * 16 + (lane & 15);
  float v = (krow < Krows) ? W[(size_t)krow * HH + n] : 0.f;
  out[idx] = f2bf(v);
}

// h = relu(x@W1+b1)@W2+b2 ; writes fp32 h and bf16 mirror h_bf
__global__ __launch_bounds__(128) void embed_kernel(
    const float* __restrict__ x,
    const float* __restrict__ W1, const float* __restrict__ b1,
    const float* __restrict__ W2, const float* __restrict__ b2,
    float* __restrict__ h, unsigned short* __restrict__ h_bf) {
  __shared__ float s_x[16][20];
  __shared__ float s_mid[16][132];
  int tid = threadIdx.x;
  int cg = tid & 31, ng = tid >> 5;
  int n0 = blockIdx.x * 16;
  for (int idx = tid; idx < 256; idx += 128) {
    int n = idx >> 4, f = idx & 15;
    s_x[n][f] = x[(size_t)(n0 + n) * FF + f];
  }
  __syncthreads();
  float4 acc[4];
  float4 bias1 = *(const float4*)&b1[cg * 4];
  #pragma unroll
  for (int ni = 0; ni < 4; ++ni) acc[ni] = bias1;
  for (int k = 0; k < FF; ++k) {
    float4 w = *(const float4*)&W1[k * HH + cg * 4];
    #pragma unroll
    for (int ni = 0; ni < 4; ++ni) fma4(acc[ni], s_x[ng * 4 + ni][k], w);
  }
  #pragma unroll
  for (int ni = 0; ni < 4; ++ni)
    *(float4*)&s_mid[ng * 4 + ni][cg * 4] = relu4(acc[ni]);
  __syncthreads();
  float4 acc2[4];
  float4 bias2 = *(const float4*)&b2[cg * 4];
  #pragma unroll
  for (int ni = 0; ni < 4; ++ni) acc2[ni] = bias2;
  for (int k = 0; k < HH; ++k) {
    float4 w = *(const float4*)&W2[k * HH + cg * 4];
    #pragma unroll
    for (int ni = 0; ni < 4; ++ni) fma4(acc2[ni], s_mid[ng * 4 + ni][k], w);
  }
  #pragma unroll
  for (int ni = 0; ni < 4; ++ni) {
    int gn = n0 + ng * 4 + ni;
    *(float4*)&h[(size_t)gn * HH + cg * 4] = acc2[ni];
    ushort4 hb;
    hb.x = f2bf(acc2[ni].x); hb.y = f2bf(acc2[ni].y);
    hb.z = f2bf(acc2[ni].z); hb.w = f2bf(acc2[ni].w);
    *(ushort4*)&h_bf[(size_t)gn * HH + cg * 4] = hb;
  }
}

// ---- msg phase A: src-ordered streaming GEMM, scatter y rows to dst-slot order ----
// y[e] = h[src[e]] @ W1[128:256]  (pure linear; bias/ea/dst-half handled in phase B)
// 64 src-slots/block, 4 waves col-split (wave w: out cols [w*32, w*32+32))
// LDS: 17408*2 + 512 = 35328 B
__global__ __launch_bounds__(256) void msg_phaseA(
    const unsigned short* __restrict__ h_bf,
    const unsigned short* __restrict__ w1p,   // packed [8 ks][8 t][64 lane][8 j]; src half = ks 4..7
    const int* __restrict__ src, const int* __restrict__ eid2,
    const int* __restrict__ slot_of, unsigned short* __restrict__ mbuf) {
  __shared__ unsigned short s_h[64 * 136];
  __shared__ unsigned short s_y[64 * 136];
  __shared__ int s_srcn[64];
  __shared__ int s_slot[64];
  int tid = threadIdx.x;
  int s0 = blockIdx.x * 64;
  if (tid < 64) {
    int e = eid2[s0 + tid];
    s_srcn[tid] = src[e];
    s_slot[tid] = slot_of[e];
  }
  __syncthreads();
  // streaming gather (src-sorted: consecutive slots share src -> L1 hits)
  for (int idx = tid; idx < 1024; idx += 256) {
    int e = idx >> 4, q = idx & 15;
    short8 v = *(const short8*)&h_bf[(size_t)s_srcn[e] * HH + q * 8];
    *(short8*)&s_h[e * 136 + q * 8] = v;
  }
  __syncthreads();
  int wid = tid >> 6, lane = tid & 63;
  int col = lane & 15, quad = lane >> 4;
  floatx4 acc[4][2];
  #pragma unroll
  for (int mt = 0; mt < 4; ++mt)
    #pragma unroll
    for (int t2 = 0; t2 < 2; ++t2) acc[mt][t2] = (floatx4){0.f, 0.f, 0.f, 0.f};
  for (int ks = 0; ks < 4; ++ks) {
    short8 a[4];
    #pragma unroll
    for (int mt = 0; mt < 4; ++mt)
      a[mt] = *(const short8*)&s_h[(mt * 16 + col) * 136 + ks * 32 + quad * 8];
    #pragma unroll
    for (int t2 = 0; t2 < 2; ++t2) {
      int t = wid * 2 + t2;
      short8 b = *(const short8*)&w1p[((size_t)((ks + 4) * 8 + t) * 64 + lane) * 8];
      #pragma unroll
      for (int mt = 0; mt < 4; ++mt)
        acc[mt][t2] = __builtin_amdgcn_mfma_f32_16x16x32_bf16(a[mt], b, acc[mt][t2], 0, 0, 0);
    }
  }
  // stage y rows (row-major, stride 136) then scatter full 256-B rows to mbuf
  #pragma unroll
  for (int t2 = 0; t2 < 2; ++t2) {
    int n = wid * 32 + t2 * 16 + col;
    #pragma unroll
    for (int mt = 0; mt < 4; ++mt)
      #pragma unroll
      for (int r = 0; r < 4; ++r)
        s_y[(mt * 16 + quad * 4 + r) * 136 + n] = f2bf(acc[mt][t2][r]);
  }
  __syncthreads();
  for (int idx = tid; idx < 1024; idx += 256) {
    int e = idx >> 4, q = idx & 15;
    short8 v = *(const short8*)&s_y[e * 136 + q * 8];
    *(short8*)&mbuf[(size_t)s_slot[e] * HH + q * 8] = v;
  }
}

// ---- msg phase B: dst-half GEMM + y add + stage2 + gate + CSR reduce -> agg ----
// 64 dst-slots/block, 4 waves col-split. All reads streaming (h_dst via CSR, mbuf sequential).
// LDS: 17408*3 + 1024 + 256 + 256 + 256 = 54016 B (<= 64 KB)
__global__ __launch_bounds__(256) void msg_phaseB(
    const unsigned short* __restrict__ h_bf,
    const unsigned short* __restrict__ w1p,   // dst half = ks 0..3
    const float* __restrict__ w1last,         // fp32 W1 row 256
    const float* __restrict__ b1,
    const unsigned short* __restrict__ w2p,
    const float* __restrict__ b2,
    const float* __restrict__ eW, const float* __restrict__ ebp,
    const int* __restrict__ dst, const float* __restrict__ ea,
    const int* __restrict__ eid, const unsigned short* __restrict__ mbuf,
    float* __restrict__ agg) {
  __shared__ unsigned short s_inp[64 * 136];  // h_dst rows; reused as s_stage later
  __shared__ unsigned short s_y[64 * 136];    // y rows from mbuf
  __shared__ unsigned short s_mid[64 * 136];  // stage-2 A rows
  __shared__ float s_gate[4][64];
  __shared__ float s_gateF[64];
  __shared__ int s_dst[64];
  __shared__ float s_ea[64];
  int tid = threadIdx.x;
  int s0 = blockIdx.x * 64;
  if (tid < 64) {
    int e = eid[s0 + tid];
    s_dst[tid] = dst[e];
    s_ea[tid] = ea[e];
  }
  __syncthreads();
  // h_dst rows (CSR-sorted: few distinct, streaming) + y rows (sequential mbuf)
  for (int idx = tid; idx < 1024; idx += 256) {
    int e = idx >> 4, q = idx & 15;
    short8 v = *(const short8*)&h_bf[(size_t)s_dst[e] * HH + q * 8];
    *(short8*)&s_inp[e * 136 + q * 8] = v;
  }
  for (int idx = tid; idx < 1024; idx += 256) {
    int e = idx >> 4, q = idx & 15;
    short8 v = *(const short8*)&mbuf[(size_t)(s0 + e) * HH + q * 8];
    *(short8*)&s_y[e * 136 + q * 8] = v;
  }
  __syncthreads();

  int wid = tid >> 6, lane = tid & 63;
  int col = lane & 15, quad = lane >> 4;

  // stage 1 (dst half): [64 x 128] @ [128 x 32]
  floatx4 acc[4][2];
  #pragma unroll
  for (int mt = 0; mt < 4; ++mt)
    #pragma unroll
    for (int t2 = 0; t2 < 2; ++t2) acc[mt][t2] = (floatx4){0.f, 0.f, 0.f, 0.f};
  for (int ks = 0; ks < 4; ++ks) {
    short8 a[4];
    #pragma unroll
    for (int mt = 0; mt < 4; ++mt)
      a[mt] = *(const short8*)&s_inp[(mt * 16 + col) * 136 + ks * 32 + quad * 8];
    #pragma unroll
    for (int t2 = 0; t2 < 2; ++t2) {
      int t = wid * 2 + t2;
      short8 b = *(const short8*)&w1p[((size_t)(ks * 8 + t) * 64 + lane) * 8];
      #pragma unroll
      for (int mt = 0; mt < 4; ++mt)
        acc[mt][t2] = __builtin_amdgcn_mfma_f32_16x16x32_bf16(a[mt], b, acc[mt][t2], 0, 0, 0);
    }
  }
  // epilogue 1: + y + b1 + ea*W1[256], relu -> s_mid
  #pragma unroll
  for (int t2 = 0; t2 < 2; ++t2) {
    int n = wid * 32 + t2 * 16 + col;
    float b1v = b1[n];
    float wl = w1last[n];
    #pragma unroll
    for (int mt = 0; mt < 4; ++mt)
      #pragma unroll
      for (int r = 0; r < 4; ++r) {
        int row = mt * 16 + quad * 4 + r;
        float v = acc[mt][t2][r] + bf2f(s_y[row * 136 + n]) + b1v + s_ea[row] * wl;
        s_mid[row * 136 + n] = f2bf(fmaxf(v, 0.f));
      }
  }
  __syncthreads();  // barrier B: s_mid complete; all s_inp/s_y reads done

  // stage 2: [64 x 128] @ [128 x 32]
  floatx4 acc2[4][2];
  #pragma unroll
  for (int mt = 0; mt < 4; ++mt)
    #pragma unroll
    for (int t2 = 0; t2 < 2; ++t2) acc2[mt][t2] = (floatx4){0.f, 0.f, 0.f, 0.f};
  for (int k2 = 0; k2 < 4; ++k2) {
    short8 a[4];
    #pragma unroll
    for (int mt = 0; mt < 4; ++mt)
      a[mt] = *(const short8*)&s_mid[(mt * 16 + col) * 136 + k2 * 32 + quad * 8];
    #pragma unroll
    for (int t2 = 0; t2 < 2; ++t2) {
      int t = wid * 2 + t2;
      short8 b = *(const short8*)&w2p[((size_t)(k2 * 8 + t) * 64 + lane) * 8];
      #pragma unroll
      for (int mt = 0; mt < 4; ++mt)
        acc2[mt][t2] = __builtin_amdgcn_mfma_f32_16x16x32_bf16(a[mt], b, acc2[mt][t2], 0, 0, 0);
    }
  }
  // epilogue 2: relu(+b2), partial gate dots
  float gp[4][4];
  #pragma unroll
  for (int mt = 0; mt < 4; ++mt)
    #pragma unroll
    for (int r = 0; r < 4; ++r) gp[mt][r] = 0.f;
  #pragma unroll
  for (int t2 = 0; t2 < 2; ++t2) {
    int n = wid * 32 + t2 * 16 + col;
    float b2v = b2[n];
    float ewv = eW[n];
    #pragma unroll
    for (int mt = 0; mt < 4; ++mt)
      #pragma unroll
      for (int r = 0; r < 4; ++r) {
        float v = fmaxf(acc2[mt][t2][r] + b2v, 0.f);
        acc2[mt][t2][r] = v;
        gp[mt][r] = fmaf(v, ewv, gp[mt][r]);
      }
  }
  #pragma unroll
  for (int mt = 0; mt < 4; ++mt)
    #pragma unroll
    for (int r = 0; r < 4; ++r) {
      #pragma unroll
      for (int mask = 1; mask < 16; mask <<= 1)
        gp[mt][r] += __shfl_xor(gp[mt][r], mask, 16);
    }
  if (col == 0) {
    #pragma unroll
    for (int mt = 0; mt < 4; ++mt)
      #pragma unroll
      for (int r = 0; r < 4; ++r)
        s_gate[wid][mt * 16 + quad * 4 + r] = gp[mt][r];
  }
  __syncthreads();
  if (tid < 64) {
    float s = s_gate[0][tid] + s_gate[1][tid] + s_gate[2][tid] + s_gate[3][tid];
    s_gateF[tid] = 1.f / (1.f + expf(-(s + ebp[0])));
  }
  __syncthreads();
  // stage m*gate into s_stage (= s_inp, dead since barrier B)
  unsigned short* s_stage = s_inp;
  #pragma unroll
  for (int t2 = 0; t2 < 2; ++t2) {
    int n = wid * 32 + t2 * 16 + col;
    #pragma unroll
    for (int mt = 0; mt < 4; ++mt)
      #pragma unroll
      for (int r = 0; r < 4; ++r) {
        int row = mt * 16 + quad * 4 + r;
        s_stage[row * 136 + n] = f2bf(acc2[mt][t2][r] * s_gateF[row]);
      }
  }
  __syncthreads();
  // CSR run-length reduction -> coalesced fp32 atomics
  {
    int half = tid >> 7, c = tid & 127;
    int r0 = half * 32, r1 = r0 + 32;
    float run = 0.f;
    int prev = s_dst[r0];
    for (int r = r0; r < r1; ++r) {
      int d = s_dst[r];               // wave-uniform per iteration
      if (d != prev) {
        atomicAdd(&agg[(size_t)prev * HH + c], run);
        run = 0.f; prev = d;
      }
      run += bf2f(s_stage[r * 136 + c]);
    }
    atomicAdd(&agg[(size_t)prev * HH + c], run);
  }
}

// ---- MFMA update net (identical to r8/r9, proven) ----
__global__ __launch_bounds__(128) void agg_upd_mfma(
    float* __restrict__ h, unsigned short* __restrict__ h_bf,
    float* __restrict__ agg, const int* __restrict__ offs,
    const unsigned short* __restrict__ u1p, const float* __restrict__ b1f,
    const unsigned short* __restrict__ u2p, const float* __restrict__ b2f) {
  __shared__ float s_u[16][260];
  __shared__ float s_af_f[2048];
  __shared__ unsigned short s_mid[2048];
  unsigned short* s_af = (unsigned short*)s_af_f;
  int tid = threadIdx.x;
  int n0 = blockIdx.x * 16;
  for (int idx = tid; idx < 512; idx += 128) {
    int n = idx >> 5, q = idx & 31;
    *(float4*)&s_u[n][q * 4] = *(const float4*)&h[(size_t)(n0 + n) * HH + q * 4];
  }
  int c = tid;
  for (int ni = 0; ni < 16; ++ni) {
    int gn = n0 + ni;
    float a = agg[(size_t)gn * HH + c];
    agg[(size_t)gn * HH + c] = 0.f;
    float d = (float)(offs[gn + 1] - offs[gn]);
    s_u[ni][HH + c] = a / fmaxf(d, 1.f);
  }
  __syncthreads();
  #pragma unroll
  for (int it = 0; it < 4; ++it) {
    int idx = it * 128 + tid;
    int ks = idx >> 6, ln = idx & 63;
    int m = ln & 15, qd = ln >> 4;
    int k0 = ks * 32 + qd * 8;
    short8 v;
    #pragma unroll
    for (int j = 0; j < 8; ++j) v[j] = (short)f2bf(s_u[m][k0 + j]);
    *(short8*)&s_af[idx * 8] = v;
  }
  __syncthreads();

  int wid = tid >> 6, lane = tid & 63;
  int col = lane & 15, quad = lane >> 4;

  floatx4 acc[4];
  #pragma unroll
  for (int t2 = 0; t2 < 4; ++t2) acc[t2] = (floatx4){0.f, 0.f, 0.f, 0.f};
  for (int ks = 0; ks < 8; ++ks) {
    short8 a = *(const short8*)&s_af[(ks * 64 + lane) * 8];
    #pragma unroll
    for (int t2 = 0; t2 < 4; ++t2) {
      int t = wid * 4 + t2;
      short8 b = *(const short8*)&u1p[((size_t)(ks * 8 + t) * 64 + lane) * 8];
      acc[t2] = __builtin_amdgcn_mfma_f32_16x16x32_bf16(a, b, acc[t2], 0, 0, 0);
    }
  }
  #pragma unroll
  for (int t2 = 0; t2 < 4; ++t2) {
    int n = wid * 64 + t2 * 16 + col;
    float b1v = b1f[n];
    int ks2 = n >> 5, quad2 = (n >> 3) & 3, j = n & 7;
    #pragma unroll
    for (int r = 0; r < 4; ++r) {
      int m2 = quad * 4 + r;
      float v = fmaxf(acc[t2][r] + b1v, 0.f);
      s_mid[(ks2 * 64 + quad2 * 16 + m2) * 8 + j] = f2bf(v);
    }
  }
  __syncthreads();
  floatx4 acc2[4];
  #pragma unroll
  for (int t2 = 0; t2 < 4; ++t2) acc2[t2] = (floatx4){0.f, 0.f, 0.f, 0.f};
  for (int k2 = 0; k2 < 4; ++k2) {
    short8 a = *(const short8*)&s_mid[(k2 * 64 + lane) * 8];
    #pragma unroll
    for (int t2 = 0; t2 < 4; ++t2) {
      int t = wid * 4 + t2;
      short8 b = *(const short8*)&u2p[((size_t)(k2 * 8 + t) * 64 + lane) * 8];
      acc2[t2] = __builtin_amdgcn_mfma_f32_16x16x32_bf16(a, b, acc2[t2], 0, 0, 0);
    }
  }
  float* s_out = s_af_f;
  #pragma unroll
  for (int t2 = 0; t2 < 4; ++t2) {
    int n = wid * 64 + t2 * 16 + col;
    float b2v = b2f[n];
    #pragma unroll
    for (int r = 0; r < 4; ++r)
      s_out[(quad * 4 + r) * HH + n] = acc2[t2][r] + b2v;
  }
  __syncthreads();
  for (int idx = tid; idx < 512; idx += 128) {
    int row = idx >> 5, c4 = idx & 31;
    int gn = n0 + row;
    float4 v = *(const float4*)&s_out[row * HH + c4 * 4];
    float* hp = &h[(size_t)gn * HH + c4 * 4];
    float4 old = *(const float4*)hp;
    old.x += v.x; old.y += v.y; old.z += v.z; old.w += v.w;
    *(float4*)hp = old;
    ushort4 hb;
    hb.x = f2bf(old.x); hb.y = f2bf(old.y); hb.z = f2bf(old.z); hb.w = f2bf(old.w);
    *(ushort4*)&h_bf[(size_t)gn * HH + c4 * 4] = hb;
  }
}

// ---- emergency fallback (atomic) path ----
__global__ __launch_bounds__(256) void msg_kernel(
    const float* __restrict__ h,
    const float* __restrict__ W1, const float* __restrict__ b1,
    const float* __restrict__ W2, const float* __restrict__ b2,
    const float* __restrict__ eW, const float* __restrict__ ebp,
    const int* __restrict__ src, const int* __restrict__ dst,
    const float* __restrict__ ea, float* __restrict__ agg) {
  __shared__ float s_inp[32][260];
  __shared__ float s_mid[32][132];
  __shared__ int s_dst[32];
  __shared__ int s_src[32];
  int tid = threadIdx.x;
  int cg = tid & 31, eg = tid >> 5;
  int e0 = blockIdx.x * 32;
  if (tid < 32) {
    s_dst[tid] = dst[e0 + tid];
    s_inp[tid][256] = ea[e0 + tid];
  } else if (tid < 64) {
    s_src[tid - 32] = src[e0 + tid - 32];
  }
  __syncthreads();
  for (int idx = tid; idx < 2048; idx += 256) {
    int e = idx >> 6, q = idx & 63;
    float4 v;
    if (q < 32) v = *(const float4*)&h[(size_t)s_dst[e] * HH + q * 4];
    else        v = *(const float4*)&h[(size_t)s_src[e] * HH + (q - 32) * 4];
    *(float4*)&s_inp[e][q * 4] = v;
  }
  __syncthreads();
  float4 acc[4];
  float4 bias1 = *(const float4*)&b1[cg * 4];
  #pragma unroll
  for (int ei = 0; ei < 4; ++ei) acc[ei] = bias1;
  for (int k = 0; k < 257; ++k) {
    float4 w = *(const float4*)&W1[k * HH + cg * 4];
    #pragma unroll
    for (int ei = 0; ei < 4; ++ei) fma4(acc[ei], s_inp[eg * 4 + ei][k], w);
  }
  #pragma unroll
  for (int ei = 0; ei < 4; ++ei)
    *(float4*)&s_mid[eg * 4 + ei][cg * 4] = relu4(acc[ei]);
  __syncthreads();
  float4 acc2[4];
  float4 bias2 = *(const float4*)&b2[cg * 4];
  #pragma unroll
  for (int ei = 0; ei < 4; ++ei) acc2[ei] = bias2;
  for (int k = 0; k < HH; ++k) {
    float4 w = *(const float4*)&W2[k * HH + cg * 4];
    #pragma unroll
    for (int ei = 0; ei < 4; ++ei) fma4(acc2[ei], s_mid[eg * 4 + ei][k], w);
  }
  float4 ew = *(const float4*)&eW[cg * 4];
  float eb = ebp[0];
  #pragma unroll
  for (int ei = 0; ei < 4; ++ei) {
    float4 m = relu4(acc2[ei]);
    float p = m.x * ew.x + m.y * ew.y + m.z * ew.z + m.w * ew.w;
    #pragma unroll
    for (int off = 16; off > 0; off >>= 1) p += __shfl_xor(p, off, 32);
    float gate = 1.f / (1.f + expf(-(p + eb)));
    int d = s_dst[eg * 4 + ei];
    float* dp = &agg[(size_t)d * HH + cg * 4];
    atomicAdd(dp + 0, m.x * gate);
    atomicAdd(dp + 1, m.y * gate);
    atomicAdd(dp + 2, m.z * gate);
    atomicAdd(dp + 3, m.w * gate);
  }
}

__global__ __launch_bounds__(128) void upd_kernel(
    float* __restrict__ h, float* __restrict__ agg, const int* __restrict__ deg,
    const float* __restrict__ W1, const float* __restrict__ b1,
    const float* __restrict__ W2, const float* __restrict__ b2) {
  __shared__ float s_u[16][260];
  __shared__ float s_mid[16][132];
  int tid = threadIdx.x;
  int cg = tid & 31, ng = tid >> 5;
  int n0 = blockIdx.x * 16;
  for (int idx = tid; idx < 1024; idx += 128) {
    int n = idx >> 6, q = idx & 63;
    int gn = n0 + n;
    float4 v;
    if (q < 32) {
      v = *(const float4*)&h[(size_t)gn * HH + q * 4];
    } else {
      float invd = 1.f / fmaxf((float)deg[gn], 1.f);
      float4 a = *(const float4*)&agg[(size_t)gn * HH + (q - 32) * 4];
      v = make_float4(a.x * invd, a.y * invd, a.z * invd, a.w * invd);
      *(float4*)&agg[(size_t)gn * HH + (q - 32) * 4] = make_float4(0.f, 0.f, 0.f, 0.f);
    }
    *(float4*)&s_u[n][q * 4] = v;
  }
  __syncthreads();
  float4 acc[4];
  float4 bias1 = *(const float4*)&b1[cg * 4];
  #pragma unroll
  for (int ni = 0; ni < 4; ++ni) acc[ni] = bias1;
  for (int k = 0; k < 256; ++k) {
    float4 w = *(const float4*)&W1[k * HH + cg * 4];
    #pragma unroll
    for (int ni = 0; ni < 4; ++ni) fma4(acc[ni], s_u[ng * 4 + ni][k], w);
  }
  #pragma unroll
  for (int ni = 0; ni < 4; ++ni)
    *(float4*)&s_mid[ng * 4 + ni][cg * 4] = relu4(acc[ni]);
  __syncthreads();
  float4 acc2[4];
  float4 bias2 = *(const float4*)&b2[cg * 4];
  #pragma unroll
  for (int ni = 0; ni < 4; ++ni) acc2[ni] = bias2;
  for (int k = 0; k < HH; ++k) {
    float4 w = *(const float4*)&W2[k * HH + cg * 4];
    #pragma unroll
    for (int ni = 0; ni < 4; ++ni) fma4(acc2[ni], s_mid[ng * 4 + ni][k], w);
  }
  #pragma unroll
  for (int ni = 0; ni < 4; ++ni) {
    float* hp = &h[(size_t)(n0 + ng * 4 + ni) * HH + cg * 4];
    float4 old = *(const float4*)hp;
    old.x += acc2[ni].x; old.y += acc2[ni].y; old.z += acc2[ni].z; old.w += acc2[ni].w;
    *(float4*)hp = old;
  }
}

__global__ __launch_bounds__(128) void decpool_kernel(
    const float* __restrict__ h, const int* __restrict__ batch,
    const float* __restrict__ W1, const float* __restrict__ b1,
    const float* __restrict__ W2, const float* __restrict__ b2,
    float* __restrict__ gg) {
  __shared__ float s_h[16][132];
  __shared__ float s_mid[16][132];
  __shared__ int s_b[16];
  int tid = threadIdx.x;
  int cg = tid & 31, ng = tid >> 5;
  int n0 = blockIdx.x * 16;
  if (tid < 16) s_b[tid] = batch[n0 + tid];
  for (int idx = tid; idx < 512; idx += 128) {
    int n = idx >> 5, q = idx & 31;
    *(float4*)&s_h[n][q * 4] = *(const float4*)&h[(size_t)(n0 + n) * HH + q * 4];
  }
  __syncthreads();
  float4 acc[4];
  float4 bias1 = *(const float4*)&b1[cg * 4];
  #pragma unroll
  for (int ni = 0; ni < 4; ++ni) acc[ni] = bias1;
  for (int k = 0; k < HH; ++k) {
    float4 w = *(const float4*)&W1[k * HH + cg * 4];
    #pragma unroll
    for (int ni = 0; ni < 4; ++ni) fma4(acc[ni], s_h[ng * 4 + ni][k], w);
  }
  #pragma unroll
  for (int ni = 0; ni < 4; ++ni)
    *(float4*)&s_mid[ng * 4 + ni][cg * 4] = relu4(acc[ni]);
  __syncthreads();
  float4 acc2[4];
  float4 bias2 = *(const float4*)&b2[cg * 4];
  #pragma unroll
  for (int ni = 0; ni < 4; ++ni) acc2[ni] = bias2;
  for (int k = 0; k < HH; ++k) {
    float4 w = *(const float4*)&W2[k * HH + cg * 4];
    #pragma unroll
    for (int ni = 0; ni < 4; ++ni) fma4(acc2[ni], s_mid[ng * 4 + ni][k], w);
  }
  #pragma unroll
  for (int ni = 0; ni < 4; ++ni) {
    int b = s_b[ng * 4 + ni];
    float* gp = &gg[(size_t)b * HH + cg * 4];
    atomicAdd(gp + 0, acc2[ni].x);
    atomicAdd(gp + 1, acc2[ni].y);
    atomicAdd(gp + 2, acc2[ni].z);
    atomicAdd(gp + 3, acc2[ni].w);
  }
}

__global__ __launch_bounds__(128) void head_kernel(
    const float* __restrict__ gg,
    const float* __restrict__ W1, const float* __restrict__ b1,
    const float* __restrict__ W2, const float* __restrict__ b2,
    float* __restrict__ out) {
  __shared__ float s_g[128];
  __shared__ float s_r[128];
  int g = blockIdx.x;
  int j = threadIdx.x;
  s_g[j] = gg[(size_t)g * HH + j];
  __syncthreads();
  float acc = b1[j];
  for (int k = 0; k < HH; ++k) acc = fmaf(s_g[k], W1[k * HH + j], acc);
  acc = fmaxf(acc, 0.f);
  s_r[j] = acc * W2[j];
  __syncthreads();
  if (j < 64) {
    float p = s_r[j] + s_r[j + 64];
    #pragma unroll
    for (int off = 32; off > 0; off >>= 1) p += __shfl_down(p, off, 64);
    if (j == 0) out[g] = p + b2[0];
  }
}

extern "C" void kernel_launch(void* const* d_in, const int* in_sizes, int n_in,
                              void* d_out, int out_size, void* d_ws, size_t ws_size,
                              hipStream_t stream) {
  const float* x      = (const float*)d_in[0];
  const float* pos    = (const float*)d_in[1];
  const int*   eidx   = (const int*)d_in[2];
  const int*   batch  = (const int*)d_in[3];
  const float* emb_W1 = (const float*)d_in[4];
  const float* emb_b1 = (const float*)d_in[5];
  const float* emb_W2 = (const float*)d_in[6];
  const float* emb_b2 = (const float*)d_in[7];
  const float* msg_W1 = (const float*)d_in[8];
  const float* msg_b1 = (const float*)d_in[9];
  const float* msg_W2 = (const float*)d_in[10];
  const float* msg_b2 = (const float*)d_in[11];
  const float* edge_W = (const float*)d_in[12];
  const float* edge_b = (const float*)d_in[13];
  const float* upd_W1 = (const float*)d_in[14];
  const float* upd_b1 = (const float*)d_in[15];
  const float* upd_W2 = (const float*)d_in[16];
  const float* upd_b2 = (const float*)d_in[17];
  const float* dec_W1 = (const float*)d_in[18];
  const float* dec_b1 = (const float*)d_in[19];
  const float* dec_W2 = (const float*)d_in[20];
  const float* dec_b2 = (const float*)d_in[21];
  const float* head_W1 = (const float*)d_in[22];
  const float* head_b1 = (const float*)d_in[23];
  const float* head_W2 = (const float*)d_in[24];
  const float* head_b2 = (const float*)d_in[25];

  const int* src = eidx;
  const int* dst = eidx + EE;

  const size_t W1P_L = 8 * 4096;   // shorts/layer, K=256 packs
  const size_t W2P_L = 4 * 4096;   // shorts/layer, K=128 packs

  size_t need_mfma = (size_t)NN * HH * 4        // h
                   + (size_t)NN * HH * 2        // h_bf
                   + (size_t)EE * 4             // ea
                   + (size_t)NN * HH * 4        // agg (fp32)
                   + (size_t)GGR * HH * 4       // gg
                   + (size_t)NN * 4 * 4         // deg, cursor, sdeg, cursor2
                   + (size_t)EE * 4 * 3         // eid, eid2, slot_of
                   + (size_t)EE * HH * 2        // mbuf (y rows, bf16)
                   + LL * W1P_L * 2 + LL * W2P_L * 2   // msg packs
                   + LL * W1P_L * 2 + LL * W2P_L * 2   // upd packs
                   + (size_t)(NN + 1) * 4 * 2;  // offs, offs2

  if (ws_size >= need_mfma) {
    char* p = (char*)d_ws;
    float* h            = (float*)p;            p += (size_t)NN * HH * 4;
    unsigned short* hbf = (unsigned short*)p;   p += (size_t)NN * HH * 2;
    float* ea           = (float*)p;            p += (size_t)EE * 4;
    float* agg          = (float*)p;            p += (size_t)NN * HH * 4;
    float* gg           = (float*)p;            p += (size_t)GGR * HH * 4;
    int* deg            = (int*)p;              p += (size_t)NN * 4;
    int* cursor         = (int*)p;              p += (size_t)NN * 4;
    int* sdeg           = (int*)p;              p += (size_t)NN * 4;
    int* cursor2        = (int*)p;              p += (size_t)NN * 4;
    int* eid            = (int*)p;              p += (size_t)EE * 4;
    int* eid2           = (int*)p;              p += (size_t)EE * 4;
    int* slot_of        = (int*)p;              p += (size_t)EE * 4;
    unsigned short* mb  = (unsigned short*)p;   p += (size_t)EE * HH * 2;
    unsigned short* w1p = (unsigned short*)p;   p += LL * W1P_L * 2;
    unsigned short* w2p = (unsigned short*)p;   p += LL * W2P_L * 2;
    unsigned short* u1p = (unsigned short*)p;   p += LL * W1P_L * 2;
    unsigned short* u2p = (unsigned short*)p;   p += LL * W2P_L * 2;
    int* offs           = (int*)p;              p += (size_t)(NN + 1) * 4;
    int* offs2          = (int*)p;

    // zero agg + gg + deg + cursor + sdeg + cursor2 (contiguous span)
    int nz = NN * HH + GGR * HH + 4 * NN;
    zero_kernel<<<(nz + 255) / 256, 256, 0, stream>>>(agg, nz);

    edge_prep<<<EE / 256, 256, 0, stream>>>(pos, src, dst, ea, deg, sdeg);
    scan_kernel<<<1, 1024, 0, stream>>>(deg, offs);
    scan_kernel<<<1, 1024, 0, stream>>>(sdeg, offs2);
    fill_csr<<<EE / 256, 256, 0, stream>>>(dst, offs, cursor, eid, slot_of);
    fill_csr2<<<EE / 256, 256, 0, stream>>>(src, offs2, cursor2, eid2);
    embed_kernel<<<NN / 16, 128, 0, stream>>>(x, emb_W1, emb_b1, emb_W2, emb_b2, h, hbf);
    for (int l = 0; l < LL; ++l) {
      pack_b<<<128, 256, 0, stream>>>(msg_W1 + (size_t)l * 257 * HH, 256, 8, w1p + l * W1P_L);
      pack_b<<<64, 256, 0, stream>>>(msg_W2 + (size_t)l * HH * HH, 128, 4, w2p + l * W2P_L);
      pack_b<<<128, 256, 0, stream>>>(upd_W1 + (size_t)l * 256 * HH, 256, 8, u1p + l * W1P_L);
      pack_b<<<64, 256, 0, stream>>>(upd_W2 + (size_t)l * HH * HH, 128, 4, u2p + l * W2P_L);
    }

    for (int l = 0; l < LL; ++l) {
      msg_phaseA<<<EE / 64, 256, 0, stream>>>(
          hbf, w1p + l * W1P_L, src, eid2, slot_of, mb);
      msg_phaseB<<<EE / 64, 256, 0, stream>>>(
          hbf, w1p + l * W1P_L,
          msg_W1 + (size_t)l * 257 * HH + (size_t)256 * HH,
          msg_b1 + l * HH,
          w2p + l * W2P_L, msg_b2 + l * HH,
          edge_W + l * HH, edge_b + l, dst, ea, eid, mb, agg);
      agg_upd_mfma<<<NN / 16, 128, 0, stream>>>(
          h, hbf, agg, offs, u1p + l * W1P_L, upd_b1 + l * HH,
          u2p + l * W2P_L, upd_b2 + l * HH);
    }

    decpool_kernel<<<NN / 16, 128, 0, stream>>>(h, batch, dec_W1, dec_b1, dec_W2, dec_b2, gg);
    head_kernel<<<GGR, 128, 0, stream>>>(gg, head_W1, head_b1, head_W2, head_b2, (float*)d_out);
  } else {
    // fallback: atomic path
    float* ws  = (float*)d_ws;
    float* h   = ws;
    float* ea  = h + (size_t)NN * HH;
    float* agg = ea + EE;
    float* gg  = agg + (size_t)NN * HH;
    int*   deg = (int*)(gg + (size_t)GGR * HH);
    int*   sdeg = deg + NN;
    unsigned short* hbf = (unsigned short*)(sdeg + NN);
    int nz = NN * HH + GGR * HH + 2 * NN;
    zero_kernel<<<(nz + 255) / 256, 256, 0, stream>>>(agg, nz);

    edge_prep<<<EE / 256, 256, 0, stream>>>(pos, src, dst, ea, deg, sdeg);
    embed_kernel<<<NN / 16, 128, 0, stream>>>(x, emb_W1, emb_b1, emb_W2, emb_b2, h, hbf);

    for (int l = 0; l < LL; ++l) {
      msg_kernel<<<EE / 32, 256, 0, stream>>>(
          h, msg_W1 + (size_t)l * 257 * HH, msg_b1 + l * HH,
          msg_W2 + (size_t)l * HH * HH, msg_b2 + l * HH,
          edge_W + l * HH, edge_b + l, src, dst, ea, agg);
      upd_kernel<<<NN / 16, 128, 0, stream>>>(
          h, agg, deg, upd_W1 + (size_t)l * 256 * HH, upd_b1 + l * HH,
          upd_W2 + (size_t)l * HH * HH, upd_b2 + l * HH);
    }

    decpool_kernel<<<NN / 16, 128, 0, stream>>>(h, batch, dec_W1, dec_b1, dec_W2, dec_b2, gg);
    head_kernel<<<GGR, 128, 0, stream>>>(gg, head_W1, head_b1, head_W2, head_b2, (float*)d_out);
  }
}

// Round 12
// 1400.590 us; speedup vs baseline: 5.6939x; 5.6939x over previous
//
#include <hip/hip_runtime.h>
#include <hip/hip_bf16.h>
#include <math.h>

#define NN 50000
#define EE 800000
#define GGR 1000
#define FF 16
#define HH 128
#define LL 4

typedef __attribute__((ext_vector_type(8))) short short8;
typedef __attribute__((ext_vector_type(4))) float floatx4;

__device__ __forceinline__ void fma4(float4& a, float s, float4 w) {
  a.x = fmaf(s, w.x, a.x); a.y = fmaf(s, w.y, a.y);
  a.z = fmaf(s, w.z, a.z); a.w = fmaf(s, w.w, a.w);
}
__device__ __forceinline__ float4 relu4(float4 v) {
  return make_float4(fmaxf(v.x, 0.f), fmaxf(v.y, 0.f), fmaxf(v.z, 0.f), fmaxf(v.w, 0.f));
}
__device__ __forceinline__ unsigned short f2bf(float v) {
  __hip_bfloat16 b = __float2bfloat16(v);
  return *reinterpret_cast<unsigned short*>(&b);
}
__device__ __forceinline__ float bf2f(unsigned short u) {
  unsigned int x = ((unsigned int)u) << 16;
  return __uint_as_float(x);
}

__global__ void zero_kernel(float* __restrict__ p, int n) {
  int i = blockIdx.x * blockDim.x + threadIdx.x;
  if (i < n) p[i] = 0.f;
}

// one thread per edge: edge length + in-degree count (int)
__global__ void edge_prep(const float* __restrict__ pos, const int* __restrict__ src,
                          const int* __restrict__ dst, float* __restrict__ ea,
                          int* __restrict__ deg) {
  int e = blockIdx.x * 256 + threadIdx.x;
  if (e >= EE) return;
  int s = src[e], d = dst[e];
  float dx = pos[d * 3 + 0] - pos[s * 3 + 0];
  float dy = pos[d * 3 + 1] - pos[s * 3 + 1];
  float dz = pos[d * 3 + 2] - pos[s * 3 + 2];
  ea[e] = sqrtf(dx * dx + dy * dy + dz * dz);
  atomicAdd(&deg[d], 1);
}

// exclusive scan of deg[NN] -> offs[NN+1]; single block of 1024
__global__ __launch_bounds__(1024) void scan_kernel(const int* __restrict__ cnt,
                                                    int* __restrict__ offs) {
  __shared__ int s_part[1024];
  int t = threadIdx.x;
  const int CH = (NN + 1023) / 1024;
  int lo = t * CH;
  int hi = lo + CH; if (hi > NN) hi = NN; if (lo > NN) lo = NN;
  int sum = 0;
  for (int i = lo; i < hi; ++i) sum += cnt[i];
  s_part[t] = sum;
  __syncthreads();
  for (int off = 1; off < 1024; off <<= 1) {
    int v = (t >= off) ? s_part[t - off] : 0;
    __syncthreads();
    s_part[t] += v;
    __syncthreads();
  }
  int run = (t == 0) ? 0 : s_part[t - 1];
  for (int i = lo; i < hi; ++i) { offs[i] = run; run += cnt[i]; }
  if (t == 1023) offs[NN] = s_part[1023];
}

// assign each edge a slot in its dst bucket
__global__ void fill_csr(const int* __restrict__ dst, const int* __restrict__ offs,
                         int* __restrict__ cursor, int* __restrict__ eid) {
  int e = blockIdx.x * 256 + threadIdx.x;
  if (e >= EE) return;
  int d = dst[e];
  int p = atomicAdd(&cursor[d], 1);
  eid[offs[d] + p] = e;
}

// fused weight packer: all 4 layers x {msg W1, msg W2, upd W1, upd W2} in ONE launch.
// B-fragment order: out[((ks*8+t)*64+lane)*8+j] = W[ks*32+(lane>>4)*8+j][t*16+(lane&15)]
// per-layer segment sizes (shorts): msgW1 32768, msgW2 16384, updW1 32768, updW2 16384
__global__ void pack_all(const float* __restrict__ msg_W1, const float* __restrict__ msg_W2,
                         const float* __restrict__ upd_W1, const float* __restrict__ upd_W2,
                         unsigned short* __restrict__ w1p, unsigned short* __restrict__ w2p,
                         unsigned short* __restrict__ u1p, unsigned short* __restrict__ u2p) {
  int idx = blockIdx.x * 256 + threadIdx.x;   // grid = LL*98304 threads
  int l = idx / 98304, r = idx % 98304;
  const float* W; unsigned short* out; int roff;
  if (r < 32768)      { W = msg_W1 + (size_t)l * 257 * HH; out = w1p + (size_t)l * 32768; roff = r; }
  else if (r < 49152) { W = msg_W2 + (size_t)l * HH * HH;  out = w2p + (size_t)l * 16384; roff = r - 32768; }
  else if (r < 81920) { W = upd_W1 + (size_t)l * 256 * HH; out = u1p + (size_t)l * 32768; roff = r - 49152; }
  else                { W = upd_W2 + (size_t)l * HH * HH;  out = u2p + (size_t)l * 16384; roff = r - 81920; }
  int j = roff & 7, lane = (roff >> 3) & 63, t = (roff >> 9) & 7, ks = roff >> 12;
  int krow = ks * 32 + (lane >> 4) * 8 + j;
  int n = t * 16 + (lane & 15);
  out[roff] = f2bf(W[(size_t)krow * HH + n]);
}

// h = relu(x@W1+b1)@W2+b2 ; writes fp32 h and bf16 mirror h_bf
__global__ __launch_bounds__(128) void embed_kernel(
    const float* __restrict__ x,
    const float* __restrict__ W1, const float* __restrict__ b1,
    const float* __restrict__ W2, const float* __restrict__ b2,
    float* __restrict__ h, unsigned short* __restrict__ h_bf) {
  __shared__ float s_x[16][20];
  __shared__ float s_mid[16][132];
  int tid = threadIdx.x;
  int cg = tid & 31, ng = tid >> 5;
  int n0 = blockIdx.x * 16;
  for (int idx = tid; idx < 256; idx += 128) {
    int n = idx >> 4, f = idx & 15;
    s_x[n][f] = x[(size_t)(n0 + n) * FF + f];
  }
  __syncthreads();
  float4 acc[4];
  float4 bias1 = *(const float4*)&b1[cg * 4];
  #pragma unroll
  for (int ni = 0; ni < 4; ++ni) acc[ni] = bias1;
  for (int k = 0; k < FF; ++k) {
    float4 w = *(const float4*)&W1[k * HH + cg * 4];
    #pragma unroll
    for (int ni = 0; ni < 4; ++ni) fma4(acc[ni], s_x[ng * 4 + ni][k], w);
  }
  #pragma unroll
  for (int ni = 0; ni < 4; ++ni)
    *(float4*)&s_mid[ng * 4 + ni][cg * 4] = relu4(acc[ni]);
  __syncthreads();
  float4 acc2[4];
  float4 bias2 = *(const float4*)&b2[cg * 4];
  #pragma unroll
  for (int ni = 0; ni < 4; ++ni) acc2[ni] = bias2;
  for (int k = 0; k < HH; ++k) {
    float4 w = *(const float4*)&W2[k * HH + cg * 4];
    #pragma unroll
    for (int ni = 0; ni < 4; ++ni) fma4(acc2[ni], s_mid[ng * 4 + ni][k], w);
  }
  #pragma unroll
  for (int ni = 0; ni < 4; ++ni) {
    int gn = n0 + ng * 4 + ni;
    *(float4*)&h[(size_t)gn * HH + cg * 4] = acc2[ni];
    ushort4 hb;
    hb.x = f2bf(acc2[ni].x); hb.y = f2bf(acc2[ni].y);
    hb.z = f2bf(acc2[ni].z); hb.w = f2bf(acc2[ni].w);
    *(ushort4*)&h_bf[(size_t)gn * HH + cg * 4] = hb;
  }
}

// ---- MFMA edge message net, col-split waves (B-fragment reuse x4) — r9-proven ----
// 64 slots/block, 4 waves; wave w computes ALL 64 edges x cols [w*32, w*32+32)
// LDS budget: 33792 + 17408 + 1024 + 256 + 768 = 53248 B  (<= 64 KB)
__global__ __launch_bounds__(256) void msg_mfma(
    const unsigned short* __restrict__ h_bf,
    const unsigned short* __restrict__ w1p,   // packed [8 ks][8 t][64 lane][8 j]
    const float* __restrict__ w1last,         // fp32 W1 row 256
    const float* __restrict__ b1,
    const unsigned short* __restrict__ w2p,   // packed [4 ks][8 t][64 lane][8 j]
    const float* __restrict__ b2,
    const float* __restrict__ eW, const float* __restrict__ ebp,
    const int* __restrict__ src, const int* __restrict__ dst,
    const float* __restrict__ ea, const int* __restrict__ eid,
    float* __restrict__ agg) {
  __shared__ unsigned short s_inp[64][264];  // [h_dst(128) | h_src(128)]
  __shared__ unsigned short s_mid[64][136];  // mid rows; reused as msg staging
  __shared__ float s_gate[4][64];            // per-wave partial gate dots
  __shared__ float s_gateF[64];              // final sigmoid gate per edge
  __shared__ int s_dst[64];
  __shared__ int s_src[64];
  __shared__ float s_ea[64];
  int tid = threadIdx.x;
  int s0 = blockIdx.x * 64;
  if (tid < 64) {
    int e = eid[s0 + tid];
    s_dst[tid] = dst[e];
    s_src[tid] = src[e];
    s_ea[tid] = ea[e];
  }
  __syncthreads();
  // gather h_bf rows: [h_dst | h_src] -> s_inp
  for (int idx = tid; idx < 2048; idx += 256) {
    int e = idx >> 5, q = idx & 31;
    int node = (q < 16) ? s_dst[e] : s_src[e];
    int c = (q & 15) * 8;
    short8 v = *(const short8*)&h_bf[(size_t)node * HH + c];
    *(short8*)&s_inp[e][(q < 16 ? 0 : 128) + c] = v;
  }
  __syncthreads();

  int wid = tid >> 6, lane = tid & 63;
  int col = lane & 15, quad = lane >> 4;

  // stage 1: [64 x 256] @ [256 x 32]  (this wave's t-tiles: wid*2, wid*2+1)
  floatx4 acc[4][2];
  #pragma unroll
  for (int mt = 0; mt < 4; ++mt)
    #pragma unroll
    for (int t2 = 0; t2 < 2; ++t2) acc[mt][t2] = (floatx4){0.f, 0.f, 0.f, 0.f};
  for (int ks = 0; ks < 8; ++ks) {
    short8 a[4];
    #pragma unroll
    for (int mt = 0; mt < 4; ++mt)
      a[mt] = *(const short8*)&s_inp[mt * 16 + col][ks * 32 + quad * 8];
    #pragma unroll
    for (int t2 = 0; t2 < 2; ++t2) {
      int t = wid * 2 + t2;
      short8 b = *(const short8*)&w1p[((size_t)(ks * 8 + t) * 64 + lane) * 8];
      #pragma unroll
      for (int mt = 0; mt < 4; ++mt)
        acc[mt][t2] = __builtin_amdgcn_mfma_f32_16x16x32_bf16(a[mt], b, acc[mt][t2], 0, 0, 0);
    }
  }
  // epilogue 1: + b1 + ea*W1[256] (exact fp32 rank-1), relu -> s_mid (this wave's cols)
  #pragma unroll
  for (int t2 = 0; t2 < 2; ++t2) {
    int n = wid * 32 + t2 * 16 + col;
    float b1v = b1[n];
    float wl = w1last[n];
    #pragma unroll
    for (int mt = 0; mt < 4; ++mt)
      #pragma unroll
      for (int r = 0; r < 4; ++r) {
        int row = mt * 16 + quad * 4 + r;
        float v = acc[mt][t2][r] + b1v + s_ea[row] * wl;
        s_mid[row][n] = f2bf(fmaxf(v, 0.f));
      }
  }
  __syncthreads();  // s_mid complete across all waves (full 128 cols)

  // stage 2: [64 x 128] @ [128 x 32]
  floatx4 acc2[4][2];
  #pragma unroll
  for (int mt = 0; mt < 4; ++mt)
    #pragma unroll
    for (int t2 = 0; t2 < 2; ++t2) acc2[mt][t2] = (floatx4){0.f, 0.f, 0.f, 0.f};
  for (int k2 = 0; k2 < 4; ++k2) {
    short8 a[4];
    #pragma unroll
    for (int mt = 0; mt < 4; ++mt)
      a[mt] = *(const short8*)&s_mid[mt * 16 + col][k2 * 32 + quad * 8];
    #pragma unroll
    for (int t2 = 0; t2 < 2; ++t2) {
      int t = wid * 2 + t2;
      short8 b = *(const short8*)&w2p[((size_t)(k2 * 8 + t) * 64 + lane) * 8];
      #pragma unroll
      for (int mt = 0; mt < 4; ++mt)
        acc2[mt][t2] = __builtin_amdgcn_mfma_f32_16x16x32_bf16(a[mt], b, acc2[mt][t2], 0, 0, 0);
    }
  }
  // epilogue 2: relu(+b2), partial gate dot over this wave's 32 cols
  float gp[4][4];
  #pragma unroll
  for (int mt = 0; mt < 4; ++mt)
    #pragma unroll
    for (int r = 0; r < 4; ++r) gp[mt][r] = 0.f;
  #pragma unroll
  for (int t2 = 0; t2 < 2; ++t2) {
    int n = wid * 32 + t2 * 16 + col;
    float b2v = b2[n];
    float ewv = eW[n];
    #pragma unroll
    for (int mt = 0; mt < 4; ++mt)
      #pragma unroll
      for (int r = 0; r < 4; ++r) {
        float v = fmaxf(acc2[mt][t2][r] + b2v, 0.f);
        acc2[mt][t2][r] = v;
        gp[mt][r] = fmaf(v, ewv, gp[mt][r]);
      }
  }
  #pragma unroll
  for (int mt = 0; mt < 4; ++mt)
    #pragma unroll
    for (int r = 0; r < 4; ++r) {
      #pragma unroll
      for (int mask = 1; mask < 16; mask <<= 1)
        gp[mt][r] += __shfl_xor(gp[mt][r], mask, 16);
    }
  if (col == 0) {
    #pragma unroll
    for (int mt = 0; mt < 4; ++mt)
      #pragma unroll
      for (int r = 0; r < 4; ++r)
        s_gate[wid][mt * 16 + quad * 4 + r] = gp[mt][r];
  }
  __syncthreads();  // partial gates visible; all stage-2 s_mid reads done
  if (tid < 64) {
    float s = s_gate[0][tid] + s_gate[1][tid] + s_gate[2][tid] + s_gate[3][tid];
    s_gateF[tid] = 1.f / (1.f + expf(-(s + ebp[0])));
  }
  __syncthreads();
  // stage m*gate (bf16) into s_mid (this wave's cols; full rows after all waves)
  #pragma unroll
  for (int t2 = 0; t2 < 2; ++t2) {
    int n = wid * 32 + t2 * 16 + col;
    #pragma unroll
    for (int mt = 0; mt < 4; ++mt)
      #pragma unroll
      for (int r = 0; r < 4; ++r) {
        int row = mt * 16 + quad * 4 + r;
        s_mid[row][n] = f2bf(acc2[mt][t2][r] * s_gateF[row]);
      }
  }
  __syncthreads();  // all staged rows visible block-wide
  // CSR run-length reduction -> coalesced fp32 atomics
  {
    int half = tid >> 7, c = tid & 127;
    int r0 = half * 32, r1 = r0 + 32;
    float run = 0.f;
    int prev = s_dst[r0];
    for (int r = r0; r < r1; ++r) {
      int d = s_dst[r];               // wave-uniform per iteration
      if (d != prev) {
        atomicAdd(&agg[(size_t)prev * HH + c], run);
        run = 0.f; prev = d;
      }
      run += bf2f(s_mid[r][c]);
    }
    atomicAdd(&agg[(size_t)prev * HH + c], run);
  }
}

// ---- MFMA update net (r8/r9-proven) ----
// 16 nodes/block, 128 threads (2 waves). Wave w computes out channels [w*64, w*64+64).
// LDS: 16640 + 8192 + 4096 = 28928 B
__global__ __launch_bounds__(128) void agg_upd_mfma(
    float* __restrict__ h, unsigned short* __restrict__ h_bf,
    float* __restrict__ agg, const int* __restrict__ offs,
    const unsigned short* __restrict__ u1p, const float* __restrict__ b1f,
    const unsigned short* __restrict__ u2p, const float* __restrict__ b2f) {
  __shared__ float s_u[16][260];            // [h(128) | agg/deg(128)] fp32
  __shared__ float s_af_f[2048];            // A-frag K=256 (bf16); later fp32 out 16x128
  __shared__ unsigned short s_mid[2048];    // A-frag K=128
  unsigned short* s_af = (unsigned short*)s_af_f;
  int tid = threadIdx.x;
  int n0 = blockIdx.x * 16;
  for (int idx = tid; idx < 512; idx += 128) {
    int n = idx >> 5, q = idx & 31;
    *(float4*)&s_u[n][q * 4] = *(const float4*)&h[(size_t)(n0 + n) * HH + q * 4];
  }
  int c = tid;
  for (int ni = 0; ni < 16; ++ni) {
    int gn = n0 + ni;
    float a = agg[(size_t)gn * HH + c];
    agg[(size_t)gn * HH + c] = 0.f;
    float d = (float)(offs[gn + 1] - offs[gn]);
    s_u[ni][HH + c] = a / fmaxf(d, 1.f);
  }
  __syncthreads();   // (1) s_u complete
  #pragma unroll
  for (int it = 0; it < 4; ++it) {
    int idx = it * 128 + tid;        // 0..511
    int ks = idx >> 6, ln = idx & 63;
    int m = ln & 15, qd = ln >> 4;
    int k0 = ks * 32 + qd * 8;
    short8 v;
    #pragma unroll
    for (int j = 0; j < 8; ++j) v[j] = (short)f2bf(s_u[m][k0 + j]);
    *(short8*)&s_af[idx * 8] = v;
  }
  __syncthreads();   // (2) s_af complete

  int wid = tid >> 6, lane = tid & 63;
  int col = lane & 15, quad = lane >> 4;

  floatx4 acc[4];
  #pragma unroll
  for (int t2 = 0; t2 < 4; ++t2) acc[t2] = (floatx4){0.f, 0.f, 0.f, 0.f};
  for (int ks = 0; ks < 8; ++ks) {
    short8 a = *(const short8*)&s_af[(ks * 64 + lane) * 8];
    #pragma unroll
    for (int t2 = 0; t2 < 4; ++t2) {
      int t = wid * 4 + t2;
      short8 b = *(const short8*)&u1p[((size_t)(ks * 8 + t) * 64 + lane) * 8];
      acc[t2] = __builtin_amdgcn_mfma_f32_16x16x32_bf16(a, b, acc[t2], 0, 0, 0);
    }
  }
  #pragma unroll
  for (int t2 = 0; t2 < 4; ++t2) {
    int n = wid * 64 + t2 * 16 + col;
    float b1v = b1f[n];
    int ks2 = n >> 5, quad2 = (n >> 3) & 3, j = n & 7;
    #pragma unroll
    for (int r = 0; r < 4; ++r) {
      int m2 = quad * 4 + r;
      float v = fmaxf(acc[t2][r] + b1v, 0.f);
      s_mid[(ks2 * 64 + quad2 * 16 + m2) * 8 + j] = f2bf(v);
    }
  }
  __syncthreads();   // (3) s_mid complete
  floatx4 acc2[4];
  #pragma unroll
  for (int t2 = 0; t2 < 4; ++t2) acc2[t2] = (floatx4){0.f, 0.f, 0.f, 0.f};
  for (int k2 = 0; k2 < 4; ++k2) {
    short8 a = *(const short8*)&s_mid[(k2 * 64 + lane) * 8];
    #pragma unroll
    for (int t2 = 0; t2 < 4; ++t2) {
      int t = wid * 4 + t2;
      short8 b = *(const short8*)&u2p[((size_t)(k2 * 8 + t) * 64 + lane) * 8];
      acc2[t2] = __builtin_amdgcn_mfma_f32_16x16x32_bf16(a, b, acc2[t2], 0, 0, 0);
    }
  }
  float* s_out = s_af_f;   // 16 rows x 128 fp32 (aliases s_af; safe after barrier 3)
  #pragma unroll
  for (int t2 = 0; t2 < 4; ++t2) {
    int n = wid * 64 + t2 * 16 + col;
    float b2v = b2f[n];
    #pragma unroll
    for (int r = 0; r < 4; ++r)
      s_out[(quad * 4 + r) * HH + n] = acc2[t2][r] + b2v;
  }
  __syncthreads();   // (4) s_out complete
  for (int idx = tid; idx < 512; idx += 128) {
    int row = idx >> 5, c4 = idx & 31;
    int gn = n0 + row;
    float4 v = *(const float4*)&s_out[row * HH + c4 * 4];
    float* hp = &h[(size_t)gn * HH + c4 * 4];
    float4 old = *(const float4*)hp;
    old.x += v.x; old.y += v.y; old.z += v.z; old.w += v.w;
    *(float4*)hp = old;
    ushort4 hb;
    hb.x = f2bf(old.x); hb.y = f2bf(old.y); hb.z = f2bf(old.z); hb.w = f2bf(old.w);
    *(ushort4*)&h_bf[(size_t)gn * HH + c4 * 4] = hb;
  }
}

// ---- emergency fallback (atomic) path ----
__global__ __launch_bounds__(256) void msg_kernel(
    const float* __restrict__ h,
    const float* __restrict__ W1, const float* __restrict__ b1,
    const float* __restrict__ W2, const float* __restrict__ b2,
    const float* __restrict__ eW, const float* __restrict__ ebp,
    const int* __restrict__ src, const int* __restrict__ dst,
    const float* __restrict__ ea, float* __restrict__ agg) {
  __shared__ float s_inp[32][260];
  __shared__ float s_mid[32][132];
  __shared__ int s_dst[32];
  __shared__ int s_src[32];
  int tid = threadIdx.x;
  int cg = tid & 31, eg = tid >> 5;
  int e0 = blockIdx.x * 32;
  if (tid < 32) {
    s_dst[tid] = dst[e0 + tid];
    s_inp[tid][256] = ea[e0 + tid];
  } else if (tid < 64) {
    s_src[tid - 32] = src[e0 + tid - 32];
  }
  __syncthreads();
  for (int idx = tid; idx < 2048; idx += 256) {
    int e = idx >> 6, q = idx & 63;
    float4 v;
    if (q < 32) v = *(const float4*)&h[(size_t)s_dst[e] * HH + q * 4];
    else        v = *(const float4*)&h[(size_t)s_src[e] * HH + (q - 32) * 4];
    *(float4*)&s_inp[e][q * 4] = v;
  }
  __syncthreads();
  float4 acc[4];
  float4 bias1 = *(const float4*)&b1[cg * 4];
  #pragma unroll
  for (int ei = 0; ei < 4; ++ei) acc[ei] = bias1;
  for (int k = 0; k < 257; ++k) {
    float4 w = *(const float4*)&W1[k * HH + cg * 4];
    #pragma unroll
    for (int ei = 0; ei < 4; ++ei) fma4(acc[ei], s_inp[eg * 4 + ei][k], w);
  }
  #pragma unroll
  for (int ei = 0; ei < 4; ++ei)
    *(float4*)&s_mid[eg * 4 + ei][cg * 4] = relu4(acc[ei]);
  __syncthreads();
  float4 acc2[4];
  float4 bias2 = *(const float4*)&b2[cg * 4];
  #pragma unroll
  for (int ei = 0; ei < 4; ++ei) acc2[ei] = bias2;
  for (int k = 0; k < HH; ++k) {
    float4 w = *(const float4*)&W2[k * HH + cg * 4];
    #pragma unroll
    for (int ei = 0; ei < 4; ++ei) fma4(acc2[ei], s_mid[eg * 4 + ei][k], w);
  }
  float4 ew = *(const float4*)&eW[cg * 4];
  float eb = ebp[0];
  #pragma unroll
  for (int ei = 0; ei < 4; ++ei) {
    float4 m = relu4(acc2[ei]);
    float p = m.x * ew.x + m.y * ew.y + m.z * ew.z + m.w * ew.w;
    #pragma unroll
    for (int off = 16; off > 0; off >>= 1) p += __shfl_xor(p, off, 32);
    float gate = 1.f / (1.f + expf(-(p + eb)));
    int d = s_dst[eg * 4 + ei];
    float* dp = &agg[(size_t)d * HH + cg * 4];
    atomicAdd(dp + 0, m.x * gate);
    atomicAdd(dp + 1, m.y * gate);
    atomicAdd(dp + 2, m.z * gate);
    atomicAdd(dp + 3, m.w * gate);
  }
}

__global__ __launch_bounds__(128) void upd_kernel(
    float* __restrict__ h, float* __restrict__ agg, const int* __restrict__ deg,
    const float* __restrict__ W1, const float* __restrict__ b1,
    const float* __restrict__ W2, const float* __restrict__ b2) {
  __shared__ float s_u[16][260];
  __shared__ float s_mid[16][132];
  int tid = threadIdx.x;
  int cg = tid & 31, ng = tid >> 5;
  int n0 = blockIdx.x * 16;
  for (int idx = tid; idx < 1024; idx += 128) {
    int n = idx >> 6, q = idx & 63;
    int gn = n0 + n;
    float4 v;
    if (q < 32) {
      v = *(const float4*)&h[(size_t)gn * HH + q * 4];
    } else {
      float invd = 1.f / fmaxf((float)deg[gn], 1.f);
      float4 a = *(const float4*)&agg[(size_t)gn * HH + (q - 32) * 4];
      v = make_float4(a.x * invd, a.y * invd, a.z * invd, a.w * invd);
      *(float4*)&agg[(size_t)gn * HH + (q - 32) * 4] = make_float4(0.f, 0.f, 0.f, 0.f);
    }
    *(float4*)&s_u[n][q * 4] = v;
  }
  __syncthreads();
  float4 acc[4];
  float4 bias1 = *(const float4*)&b1[cg * 4];
  #pragma unroll
  for (int ni = 0; ni < 4; ++ni) acc[ni] = bias1;
  for (int k = 0; k < 256; ++k) {
    float4 w = *(const float4*)&W1[k * HH + cg * 4];
    #pragma unroll
    for (int ni = 0; ni < 4; ++ni) fma4(acc[ni], s_u[ng * 4 + ni][k], w);
  }
  #pragma unroll
  for (int ni = 0; ni < 4; ++ni)
    *(float4*)&s_mid[ng * 4 + ni][cg * 4] = relu4(acc[ni]);
  __syncthreads();
  float4 acc2[4];
  float4 bias2 = *(const float4*)&b2[cg * 4];
  #pragma unroll
  for (int ni = 0; ni < 4; ++ni) acc2[ni] = bias2;
  for (int k = 0; k < HH; ++k) {
    float4 w = *(const float4*)&W2[k * HH + cg * 4];
    #pragma unroll
    for (int ni = 0; ni < 4; ++ni) fma4(acc2[ni], s_mid[ng * 4 + ni][k], w);
  }
  #pragma unroll
  for (int ni = 0; ni < 4; ++ni) {
    float* hp = &h[(size_t)(n0 + ng * 4 + ni) * HH + cg * 4];
    float4 old = *(const float4*)hp;
    old.x += acc2[ni].x; old.y += acc2[ni].y; old.z += acc2[ni].z; old.w += acc2[ni].w;
    *(float4*)hp = old;
  }
}

__global__ __launch_bounds__(128) void decpool_kernel(
    const float* __restrict__ h, const int* __restrict__ batch,
    const float* __restrict__ W1, const float* __restrict__ b1,
    const float* __restrict__ W2, const float* __restrict__ b2,
    float* __restrict__ gg) {
  __shared__ float s_h[16][132];
  __shared__ float s_mid[16][132];
  __shared__ int s_b[16];
  int tid = threadIdx.x;
  int cg = tid & 31, ng = tid >> 5;
  int n0 = blockIdx.x * 16;
  if (tid < 16) s_b[tid] = batch[n0 + tid];
  for (int idx = tid; idx < 512; idx += 128) {
    int n = idx >> 5, q = idx & 31;
    *(float4*)&s_h[n][q * 4] = *(const float4*)&h[(size_t)(n0 + n) * HH + q * 4];
  }
  __syncthreads();
  float4 acc[4];
  float4 bias1 = *(const float4*)&b1[cg * 4];
  #pragma unroll
  for (int ni = 0; ni < 4; ++ni) acc[ni] = bias1;
  for (int k = 0; k < HH; ++k) {
    float4 w = *(const float4*)&W1[k * HH + cg * 4];
    #pragma unroll
    for (int ni = 0; ni < 4; ++ni) fma4(acc[ni], s_h[ng * 4 + ni][k], w);
  }
  #pragma unroll
  for (int ni = 0; ni < 4; ++ni)
    *(float4*)&s_mid[ng * 4 + ni][cg * 4] = relu4(acc[ni]);
  __syncthreads();
  float4 acc2[4];
  float4 bias2 = *(const float4*)&b2[cg * 4];
  #pragma unroll
  for (int ni = 0; ni < 4; ++ni) acc2[ni] = bias2;
  for (int k = 0; k < HH; ++k) {
    float4 w = *(const float4*)&W2[k * HH + cg * 4];
    #pragma unroll
    for (int ni = 0; ni < 4; ++ni) fma4(acc2[ni], s_mid[ng * 4 + ni][k], w);
  }
  #pragma unroll
  for (int ni = 0; ni < 4; ++ni) {
    int b = s_b[ng * 4 + ni];
    float* gp = &gg[(size_t)b * HH + cg * 4];
    atomicAdd(gp + 0, acc2[ni].x);
    atomicAdd(gp + 1, acc2[ni].y);
    atomicAdd(gp + 2, acc2[ni].z);
    atomicAdd(gp + 3, acc2[ni].w);
  }
}

__global__ __launch_bounds__(128) void head_kernel(
    const float* __restrict__ gg,
    const float* __restrict__ W1, const float* __restrict__ b1,
    const float* __restrict__ W2, const float* __restrict__ b2,
    float* __restrict__ out) {
  __shared__ float s_g[128];
  __shared__ float s_r[128];
  int g = blockIdx.x;
  int j = threadIdx.x;
  s_g[j] = gg[(size_t)g * HH + j];
  __syncthreads();
  float acc = b1[j];
  for (int k = 0; k < HH; ++k) acc = fmaf(s_g[k], W1[k * HH + j], acc);
  acc = fmaxf(acc, 0.f);
  s_r[j] = acc * W2[j];
  __syncthreads();
  if (j < 64) {
    float p = s_r[j] + s_r[j + 64];
    #pragma unroll
    for (int off = 32; off > 0; off >>= 1) p += __shfl_down(p, off, 64);
    if (j == 0) out[g] = p + b2[0];
  }
}

extern "C" void kernel_launch(void* const* d_in, const int* in_sizes, int n_in,
                              void* d_out, int out_size, void* d_ws, size_t ws_size,
                              hipStream_t stream) {
  const float* x      = (const float*)d_in[0];
  const float* pos    = (const float*)d_in[1];
  const int*   eidx   = (const int*)d_in[2];
  const int*   batch  = (const int*)d_in[3];
  const float* emb_W1 = (const float*)d_in[4];
  const float* emb_b1 = (const float*)d_in[5];
  const float* emb_W2 = (const float*)d_in[6];
  const float* emb_b2 = (const float*)d_in[7];
  const float* msg_W1 = (const float*)d_in[8];
  const float* msg_b1 = (const float*)d_in[9];
  const float* msg_W2 = (const float*)d_in[10];
  const float* msg_b2 = (const float*)d_in[11];
  const float* edge_W = (const float*)d_in[12];
  const float* edge_b = (const float*)d_in[13];
  const float* upd_W1 = (const float*)d_in[14];
  const float* upd_b1 = (const float*)d_in[15];
  const float* upd_W2 = (const float*)d_in[16];
  const float* upd_b2 = (const float*)d_in[17];
  const float* dec_W1 = (const float*)d_in[18];
  const float* dec_b1 = (const float*)d_in[19];
  const float* dec_W2 = (const float*)d_in[20];
  const float* dec_b2 = (const float*)d_in[21];
  const float* head_W1 = (const float*)d_in[22];
  const float* head_b1 = (const float*)d_in[23];
  const float* head_W2 = (const float*)d_in[24];
  const float* head_b2 = (const float*)d_in[25];

  const int* src = eidx;
  const int* dst = eidx + EE;

  const size_t W1P_L = 8 * 4096;   // shorts/layer, K=256 packs
  const size_t W2P_L = 4 * 4096;   // shorts/layer, K=128 packs

  size_t need_mfma = (size_t)NN * HH * 4        // h
                   + (size_t)NN * HH * 2        // h_bf
                   + (size_t)EE * 4             // ea
                   + (size_t)NN * HH * 4        // agg (fp32)
                   + (size_t)GGR * HH * 4       // gg
                   + (size_t)NN * 4             // deg
                   + (size_t)NN * 4             // cursor
                   + (size_t)EE * 4             // eid
                   + LL * W1P_L * 2             // w1p (msg)
                   + LL * W2P_L * 2             // w2p (msg)
                   + LL * W1P_L * 2             // u1p (upd)
                   + LL * W2P_L * 2             // u2p (upd)
                   + (size_t)(NN + 1) * 4;      // offs

  if (ws_size >= need_mfma) {
    char* p = (char*)d_ws;
    float* h            = (float*)p;            p += (size_t)NN * HH * 4;
    unsigned short* hbf = (unsigned short*)p;   p += (size_t)NN * HH * 2;
    float* ea           = (float*)p;            p += (size_t)EE * 4;
    float* agg          = (float*)p;            p += (size_t)NN * HH * 4;
    float* gg           = (float*)p;            p += (size_t)GGR * HH * 4;
    int* deg            = (int*)p;              p += (size_t)NN * 4;
    int* cursor         = (int*)p;              p += (size_t)NN * 4;
    int* eid            = (int*)p;              p += (size_t)EE * 4;
    unsigned short* w1p = (unsigned short*)p;   p += LL * W1P_L * 2;
    unsigned short* w2p = (unsigned short*)p;   p += LL * W2P_L * 2;
    unsigned short* u1p = (unsigned short*)p;   p += LL * W1P_L * 2;
    unsigned short* u2p = (unsigned short*)p;   p += LL * W2P_L * 2;
    int* offs           = (int*)p;

    // zero agg + gg + deg + cursor (contiguous span starting at agg)
    int nz = NN * HH + GGR * HH + NN + NN;
    zero_kernel<<<(nz + 255) / 256, 256, 0, stream>>>(agg, nz);

    edge_prep<<<EE / 256, 256, 0, stream>>>(pos, src, dst, ea, deg);
    scan_kernel<<<1, 1024, 0, stream>>>(deg, offs);
    fill_csr<<<EE / 256, 256, 0, stream>>>(dst, offs, cursor, eid);
    embed_kernel<<<NN / 16, 128, 0, stream>>>(x, emb_W1, emb_b1, emb_W2, emb_b2, h, hbf);
    // single fused pack launch: LL*98304 threads
    pack_all<<<LL * 98304 / 256, 256, 0, stream>>>(msg_W1, msg_W2, upd_W1, upd_W2,
                                                   w1p, w2p, u1p, u2p);

    for (int l = 0; l < LL; ++l) {
      msg_mfma<<<EE / 64, 256, 0, stream>>>(
          hbf, w1p + l * W1P_L,
          msg_W1 + (size_t)l * 257 * HH + (size_t)256 * HH,
          msg_b1 + l * HH,
          w2p + l * W2P_L, msg_b2 + l * HH,
          edge_W + l * HH, edge_b + l, src, dst, ea, eid, agg);
      agg_upd_mfma<<<NN / 16, 128, 0, stream>>>(
          h, hbf, agg, offs, u1p + l * W1P_L, upd_b1 + l * HH,
          u2p + l * W2P_L, upd_b2 + l * HH);
    }

    decpool_kernel<<<NN / 16, 128, 0, stream>>>(h, batch, dec_W1, dec_b1, dec_W2, dec_b2, gg);
    head_kernel<<<GGR, 128, 0, stream>>>(gg, head_W1, head_b1, head_W2, head_b2, (float*)d_out);
  } else {
    // fallback: atomic path
    float* ws  = (float*)d_ws;
    float* h   = ws;
    float* ea  = h + (size_t)NN * HH;
    float* agg = ea + EE;
    float* gg  = agg + (size_t)NN * HH;
    int*   deg = (int*)(gg + (size_t)GGR * HH);
    unsigned short* hbf = (unsigned short*)(deg + NN);
    int nz = NN * HH + GGR * HH + NN;
    zero_kernel<<<(nz + 255) / 256, 256, 0, stream>>>(agg, nz);

    edge_prep<<<EE / 256, 256, 0, stream>>>(pos, src, dst, ea, deg);
    embed_kernel<<<NN / 16, 128, 0, stream>>>(x, emb_W1, emb_b1, emb_W2, emb_b2, h, hbf);

    for (int l = 0; l < LL; ++l) {
      msg_kernel<<<EE / 32, 256, 0, stream>>>(
          h, msg_W1 + (size_t)l * 257 * HH, msg_b1 + l * HH,
          msg_W2 + (size_t)l * HH * HH, msg_b2 + l * HH,
          edge_W + l * HH, edge_b + l, src, dst, ea, agg);
      upd_kernel<<<NN / 16, 128, 0, stream>>>(
          h, agg, deg, upd_W1 + (size_t)l * 256 * HH, upd_b1 + l * HH,
          upd_W2 + (size_t)l * HH * HH, upd_b2 + l * HH);
    }

    decpool_kernel<<<NN / 16, 128, 0, stream>>>(h, batch, dec_W1, dec_b1, dec_W2, dec_b2, gg);
    head_kernel<<<GGR, 128, 0, stream>>>(gg, head_W1, head_b1, head_W2, head_b2, (float*)d_out);
  }
}